// Round 8
// baseline (601.218 us; speedup 1.0000x reference)
//
#include <hip/hip_runtime.h>

typedef __attribute__((ext_vector_type(4))) float f32x4;
typedef unsigned char u8;
typedef unsigned long long u64t;

#define BIG_NEG -1000000000.0f

static constexpr int B_  = 256;
static constexpr int SX_ = 34;
static constexpr int SY_ = 34;
static constexpr int IND = 66;   // IN_DIM
static constexpr int OP_ = 80;   // padded OUT_DIM (65 -> 80)
static constexpr int NBLK = 768; // fused grid size

__device__ __forceinline__ f32x4 mfma_fp8(long a, long b, f32x4 c) {
  return __builtin_amdgcn_mfma_f32_16x16x32_fp8_fp8(a, b, c, 0, 0, 0);
}
__device__ __forceinline__ float sigm(float x)  { return 1.0f / (1.0f + __expf(-x)); }
__device__ __forceinline__ float tanhx(float x) { return 2.0f * sigm(2.0f * x) - 1.0f; }
template <bool HI>
__device__ __forceinline__ unsigned pk2(float a, float b, unsigned old) {
  return __builtin_amdgcn_cvt_pk_fp8_f32(a, b, (int)old, HI);
}
// select element j (runtime 0..3) of f32x4 without dynamic indexing
__device__ __forceinline__ float rsel(f32x4 a, int j) {
  float lo = (j & 1) ? a[1] : a[0];
  float hi = (j & 1) ? a[3] : a[2];
  return (j & 2) ? hi : lo;
}

// grid-wide phase barrier: per-wave drain -> tid0 release-add -> poll -> acquire.
// All 768 blocks resident (3/CU exact fit) => cannot deadlock.
__device__ __forceinline__ void phase_barrier(unsigned* __restrict__ ctr) {
  __asm__ volatile("s_waitcnt vmcnt(0)" ::: "memory");  // own stores reached L2
  __syncthreads();
  if (threadIdx.x == 0) {
    // RELEASE: writes back this XCD's L2 so our plain stores are LLC-visible
    __hip_atomic_fetch_add(ctr, 1u, __ATOMIC_RELEASE, __HIP_MEMORY_SCOPE_AGENT);
    int spin = 0;
    for (;;) {
      unsigned v = __hip_atomic_load(ctr, __ATOMIC_RELAXED, __HIP_MEMORY_SCOPE_AGENT);
      if (v >= (unsigned)NBLK) break;
      __builtin_amdgcn_s_sleep(2);
      if (++spin > (1 << 20)) break;   // safety exit
    }
  }
  __syncthreads();
  // ACQUIRE: invalidate L1/L2 so plain loads see other blocks' released stores
  __builtin_amdgcn_fence(__ATOMIC_ACQUIRE, "agent");
  __syncthreads();
}

// ---------------------------------------------------------------------------
// lstm chain bodies — byte-identical to the proven R3 structure.
// ---------------------------------------------------------------------------
template <int HH, int NS>
__device__ __forceinline__ void run_lstm32(
    const u8* __restrict__ w8, const float* __restrict__ E,
    bool revr, u8* __restrict__ hall, int b0, int h0,
    unsigned* __restrict__ flags, int dom0, int myid,
    u8* __restrict__ alds, u8* __restrict__ hT, const u8* __restrict__ tok_small) {
  const int tid = threadIdx.x;
  const int lane = tid & 63, w = tid >> 6;
  const int lo = lane & 15, q = lane >> 4;
  constexpr int AST = HH + 8;
  constexpr int U8C = HH / 8;
  constexpr int USH = (HH == 1024) ? 7 : 6;
  constexpr int NI  = (32 * U8C) / 256;   // 8 for HH=512
  constexpr int NK  = HH / 32;
  const int hh = lo & 7;
  const bool hi = (lo >= 8);
  const int hu_e = h0 + w * 8 + hh;

  long breg0[NK], breg1[NK];
  {
    const u8* brow0 = w8 + (size_t)((lo >> 3) * HH + hu_e) * HH + q * 8;
    const u8* brow1 = w8 + (size_t)((2 + (lo >> 3)) * HH + hu_e) * HH + q * 8;
#pragma unroll
    for (int kk = 0; kk < NK; ++kk) {
      breg0[kk] = *(const long*)(brow0 + kk * 32);
      breg1[kk] = *(const long*)(brow1 + kk * 32);
    }
  }
  float creg[4] = {0.f, 0.f, 0.f, 0.f};

  for (int t = 0; t < 34; ++t) {
    const int tpos = revr ? 33 - t : t;
    const u8* tkp = tok_small + tpos * 32;

    float ev[2][4][2];
#pragma unroll
    for (int mt = 0; mt < 2; ++mt)
#pragma unroll
      for (int rr = 0; rr < 2; ++rr) {
        int r = (hi ? 2 : 0) + rr;
        int v = tkp[mt * 16 + q * 4 + r];
        const float* e = E + (size_t)v * (4 * HH) + hu_e;
        ev[mt][0][rr] = e[0];
        ev[mt][1][rr] = e[HH];
        ev[mt][2][rr] = e[2 * HH];
        ev[mt][3][rr] = e[3 * HH];
      }

    f32x4 acc[2][2];
#pragma unroll
    for (int mt = 0; mt < 2; ++mt) {
      acc[mt][0] = (f32x4){0.f, 0.f, 0.f, 0.f};
      acc[mt][1] = (f32x4){0.f, 0.f, 0.f, 0.f};
    }

    if (t > 0) {
      if (tid < NS) {
        const unsigned tgt = (unsigned)t;
        int spin = 0;
        for (;;) {
          unsigned v = __hip_atomic_load(&flags[(dom0 + tid) * 32],
                                         __ATOMIC_RELAXED, __HIP_MEMORY_SCOPE_AGENT);
          if (__ballot(v < tgt) == 0) break;
          __builtin_amdgcn_s_sleep(1);
          if (++spin > (1 << 17)) break;
        }
      }
      __syncthreads();

      const u8* hsrc = hall + (size_t)t * (256 * HH);
      u64t tmp[NI];
#pragma unroll
      for (int ii = 0; ii < NI; ++ii) {
        int idx = tid + ii * 256;
        tmp[ii] = __hip_atomic_load(
            (const u64t*)(hsrc + (size_t)(b0 + (idx >> USH)) * HH + (idx & (U8C - 1)) * 8),
            __ATOMIC_RELAXED, __HIP_MEMORY_SCOPE_AGENT);
      }
#pragma unroll
      for (int ii = 0; ii < NI; ++ii) {
        int idx = tid + ii * 256;
        *(u64t*)&alds[(idx >> USH) * AST + (idx & (U8C - 1)) * 8] = tmp[ii];
      }
      __syncthreads();

      const u8* a0p = alds + lo * AST + q * 8;
      const u8* a1p = alds + (16 + lo) * AST + q * 8;
#pragma unroll
      for (int kk = 0; kk < NK; ++kk) {
        long a0 = *(const long*)(a0p + kk * 32);
        long a1 = *(const long*)(a1p + kk * 32);
        acc[0][0] = mfma_fp8(a0, breg0[kk], acc[0][0]);
        acc[0][1] = mfma_fp8(a0, breg1[kk], acc[0][1]);
        acc[1][0] = mfma_fp8(a1, breg0[kk], acc[1][0]);
        acc[1][1] = mfma_fp8(a1, breg1[kk], acc[1][1]);
      }
    }

#pragma unroll
    for (int mt = 0; mt < 2; ++mt) {
      f32x4 t0 = acc[mt][0], t1 = acc[mt][1];
      f32x4 p0, p1;
#pragma unroll
      for (int c2 = 0; c2 < 4; ++c2) {
        p0[c2] = __shfl_xor(t0[c2], 8, 64);
        p1[c2] = __shfl_xor(t1[c2], 8, 64);
      }
#pragma unroll
      for (int rr = 0; rr < 2; ++rr) {
        int r = (hi ? 2 : 0) + rr;
        float iv = (hi ? p0[r] : t0[r]) + ev[mt][0][rr];
        float fv = (hi ? t0[r] : p0[r]) + ev[mt][1][rr];
        float gv = (hi ? p1[r] : t1[r]) + ev[mt][2][rr];
        float ov = (hi ? t1[r] : p1[r]) + ev[mt][3][rr];
        int m = mt * 16 + q * 4 + r;
        float cold = creg[mt * 2 + rr];
        float cn = sigm(fv) * cold + sigm(iv) * tanhx(gv);
        float hn = sigm(ov) * tanhx(cn);
        creg[mt * 2 + rr] = cn;
        hT[m * 32 + w * 8 + hh] = (u8)(pk2<false>(hn, hn, 0) & 0xffu);
      }
    }
    __syncthreads();

    {
      int m = tid >> 3, cc = tid & 7;
      unsigned val = *(const unsigned*)&hT[m * 32 + cc * 4];
      u8* hdst = hall + (size_t)(t + 1) * (256 * HH);
      __hip_atomic_store((unsigned*)(hdst + (size_t)(b0 + m) * HH + h0 + cc * 4),
                         val, __ATOMIC_RELAXED, __HIP_MEMORY_SCOPE_AGENT);
    }
    if (t < 33) {
      __asm__ volatile("s_waitcnt vmcnt(0)" ::: "memory");
      __syncthreads();
      if (tid == 0)
        __hip_atomic_store(&flags[(dom0 + myid) * 32], (unsigned)(t + 1),
                           __ATOMIC_RELAXED, __HIP_MEMORY_SCOPE_AGENT);
    } else {
      __asm__ volatile("s_waitcnt vmcnt(0)" ::: "memory");
      __syncthreads();
    }
  }
}

template <int HH, int NS>
__device__ __forceinline__ void run_lstm16(
    const u8* __restrict__ w8, const float* __restrict__ E,
    u8* __restrict__ hall, int b0, int h0,
    unsigned* __restrict__ flags, int dom0, int myid,
    u8* __restrict__ alds, u8* __restrict__ hT, const u8* __restrict__ tok_small) {
  const int tid = threadIdx.x;
  const int lane = tid & 63, w = tid >> 6;
  const int lo = lane & 15, q = lane >> 4;
  constexpr int AST = HH + 8;
  constexpr int U8C = HH / 8;          // 128
  constexpr int USH = 7;               // HH = 1024
  constexpr int NI  = (32 * U8C) / 256;   // 16
  constexpr int NK  = HH / 32;         // 32
  const int g = lo & 3;
  const int u = lo >> 2;
  const int hu = h0 + w * 4 + u;

  long breg[NK];
  {
    const u8* brow = w8 + (size_t)(g * HH + hu) * HH + q * 8;
#pragma unroll
    for (int kk = 0; kk < NK; ++kk) breg[kk] = *(const long*)(brow + kk * 32);
  }
  float creg[2] = {0.f, 0.f};

  for (int t = 0; t < 34; ++t) {
    const u8* tkp = tok_small + t * 32;

    float ev[2][4];
#pragma unroll
    for (int mt = 0; mt < 2; ++mt) {
      int v = tkp[mt * 16 + q * 4 + g];
      const float* e = E + (size_t)v * (4 * HH) + hu;
      ev[mt][0] = e[0]; ev[mt][1] = e[HH]; ev[mt][2] = e[2 * HH]; ev[mt][3] = e[3 * HH];
    }

    f32x4 acc[2];
    acc[0] = (f32x4){0.f, 0.f, 0.f, 0.f};
    acc[1] = (f32x4){0.f, 0.f, 0.f, 0.f};

    if (t > 0) {
      if (tid < NS) {
        const unsigned tgt = (unsigned)t;
        int spin = 0;
        for (;;) {
          unsigned v = __hip_atomic_load(&flags[(dom0 + tid) * 32],
                                         __ATOMIC_RELAXED, __HIP_MEMORY_SCOPE_AGENT);
          if (__ballot(v < tgt) == 0) break;
          __builtin_amdgcn_s_sleep(1);
          if (++spin > (1 << 17)) break;
        }
      }
      __syncthreads();

      const u8* hsrc = hall + (size_t)t * (256 * HH);
      u64t tmp[NI];
#pragma unroll
      for (int ii = 0; ii < NI; ++ii) {
        int idx = tid + ii * 256;
        tmp[ii] = __hip_atomic_load(
            (const u64t*)(hsrc + (size_t)(b0 + (idx >> USH)) * HH + (idx & (U8C - 1)) * 8),
            __ATOMIC_RELAXED, __HIP_MEMORY_SCOPE_AGENT);
      }
#pragma unroll
      for (int ii = 0; ii < NI; ++ii) {
        int idx = tid + ii * 256;
        *(u64t*)&alds[(idx >> USH) * AST + (idx & (U8C - 1)) * 8] = tmp[ii];
      }
      __syncthreads();

      const u8* a0p = alds + lo * AST + q * 8;
      const u8* a1p = alds + (16 + lo) * AST + q * 8;
#pragma unroll
      for (int kk = 0; kk < NK; ++kk) {
        long a0 = *(const long*)(a0p + kk * 32);
        long a1 = *(const long*)(a1p + kk * 32);
        acc[0] = mfma_fp8(a0, breg[kk], acc[0]);
        acc[1] = mfma_fp8(a1, breg[kk], acc[1]);
      }
    }

#pragma unroll
    for (int mt = 0; mt < 2; ++mt) {
      f32x4 a = acc[mt];
      float own = rsel(a, g);
      float y1  = __shfl_xor(rsel(a, g ^ 1), 1, 64);
      float y2  = __shfl_xor(rsel(a, g ^ 2), 2, 64);
      float y3  = __shfl_xor(rsel(a, g ^ 3), 3, 64);
      float iv = (g == 0) ? own : (g == 1) ? y1 : (g == 2) ? y2 : y3;
      float fv = (g == 0) ? y1 : (g == 1) ? own : (g == 2) ? y3 : y2;
      float gv = (g == 0) ? y2 : (g == 1) ? y3 : (g == 2) ? own : y1;
      float ov = (g == 0) ? y3 : (g == 1) ? y2 : (g == 2) ? y1 : own;
      iv += ev[mt][0]; fv += ev[mt][1]; gv += ev[mt][2]; ov += ev[mt][3];
      int m = mt * 16 + q * 4 + g;
      float cold = creg[mt];
      float cn = sigm(fv) * cold + sigm(iv) * tanhx(gv);
      float hn = sigm(ov) * tanhx(cn);
      creg[mt] = cn;
      hT[m * 16 + w * 4 + u] = (u8)(pk2<false>(hn, hn, 0) & 0xffu);
    }
    __syncthreads();

    if (tid < 128) {
      int m = tid >> 2, cc = tid & 3;
      unsigned val = *(const unsigned*)&hT[m * 16 + cc * 4];
      u8* hdst = hall + (size_t)(t + 1) * (256 * HH);
      __hip_atomic_store((unsigned*)(hdst + (size_t)(b0 + m) * HH + h0 + cc * 4),
                         val, __ATOMIC_RELAXED, __HIP_MEMORY_SCOPE_AGENT);
    }
    if (t < 33) {
      __asm__ volatile("s_waitcnt vmcnt(0)" ::: "memory");
      __syncthreads();
      if (tid == 0)
        __hip_atomic_store(&flags[(dom0 + myid) * 32], (unsigned)(t + 1),
                           __ATOMIC_RELAXED, __HIP_MEMORY_SCOPE_AGENT);
    } else {
      __asm__ volatile("s_waitcnt vmcnt(0)" ::: "memory");
      __syncthreads();
    }
  }
}

// ---------------------------------------------------------------------------
// fused mega-kernel: phase0 prep -> B0 -> phase1 lstm -> B1 -> phase2 head
// -> B2 -> phase3 pair.  One launch instead of four.
// ---------------------------------------------------------------------------
__global__ __launch_bounds__(256, 3) void fused_all(
    const float* __restrict__ src, const float* __restrict__ tgt,
    int* __restrict__ tok_x, int* __restrict__ tok_y,
    const float* __restrict__ Wsub, const float* __restrict__ Wins,
    u8* __restrict__ Wcat,
    const float* __restrict__ Wihf, const float* __restrict__ bf,
    const float* __restrict__ Wihr, const float* __restrict__ br,
    const float* __restrict__ Wihm, const float* __restrict__ bm,
    float* __restrict__ Ef, float* __restrict__ Er, float* __restrict__ Em,
    const float* __restrict__ Whf, const float* __restrict__ Whr,
    const float* __restrict__ Whm,
    u8* __restrict__ w8f, u8* __restrict__ w8r, u8* __restrict__ w8m,
    const float* __restrict__ b_sub, const float* __restrict__ b_ins,
    float* __restrict__ lx_sub, float* __restrict__ lx_ins,
    float* __restrict__ ly_sub, float* __restrict__ ly_ins,
    u8* __restrict__ fwd_all, u8* __restrict__ rev_all, u8* __restrict__ y_all,
    float* __restrict__ out, unsigned* __restrict__ flags) {
  __shared__ u8 smem[160 * 264];          // 42240 B, union of all phases
  u8* alds = smem;                        // [0, 33024)  lstm stage
  u8* hT   = smem + 33024;                // [33024, 34048)
  u8* tok_small = smem + 34048;           // [34048, 35136)
  float* tile = (float*)smem;             // phase-0 build_E (17152 B)
  unsigned* bar = flags + 768 * 32;       // 3 barrier counters, 128B apart

  const int blk = blockIdx.x;
  const int tid = threadIdx.x;

  // ================= phase 0: prep (3428 units over 768 blocks) ============
  for (int uu = blk; uu < 3428; uu += NBLK) {
    if (uu < 68) {                        // ---- decode tokens ----
      int idx = uu * 256 + tid;
      const int half = SX_ * B_;
      const float* base = (idx < half) ? src : tgt;
      int* outp         = (idx < half) ? tok_x : tok_y;
      int k = (idx < half) ? idx : idx - half;
      const float* p = base + (size_t)k * IND;
      int tok = -1;
      for (int v = 0; v < IND; ++v) if (p[v] > 0.5f) tok = v;
      outp[k] = tok;
    } else if (uu < 228) {                // ---- pad head W -> fp8 ----
      int widx = (uu - 68) * 256 + tid;
      int row = widx >> 8;
      int wc  = widx & 255;
      int srow = row < 80 ? row : row - 80;
      const float* W = row < 80 ? Wsub : Wins;
      float f0 = 0.f, f1 = 0.f, f2 = 0.f, f3 = 0.f;
      if (srow < 65) {
        const float* p = W + (size_t)srow * 1024 + wc * 4;
        f0 = p[0]; f1 = p[1]; f2 = p[2]; f3 = p[3];
      }
      unsigned wv = pk2<false>(f0, f1, 0);
      wv = pk2<true>(f2, f3, wv);
      ((unsigned*)Wcat)[widx] = wv;
    } else if (uu < 356) {                // ---- build E (LDS transpose) ----
      int tb = uu - 228;
      const float* W; const float* bias; float* E; int H4; int n0;
      if (tb < 32)      { W = Wihf; bias = bf; E = Ef; H4 = 2048; n0 = tb * 64; }
      else if (tb < 64) { W = Wihr; bias = br; E = Er; H4 = 2048; n0 = (tb - 32) * 64; }
      else              { W = Wihm; bias = bm; E = Em; H4 = 4096; n0 = (tb - 64) * 64; }
      const float* s2 = W + (size_t)n0 * IND;
      __syncthreads();                    // protect tile reuse across uu iters
      for (int i = tid; i < 64 * IND; i += 256) {
        int n = i / IND, v = i - n * IND;
        tile[n * 67 + v] = s2[i];
      }
      __syncthreads();
      int lane = tid & 63, w2 = tid >> 6;
      float bl = bias[n0 + lane];
      for (int v = w2; v < 67; v += 4) {
        float val = (v < 66 ? tile[lane * 67 + v] : 0.f) + bl;
        E[(size_t)v * H4 + n0 + lane] = val;
      }
    } else {                              // ---- conv Whh -> fp8 ----
      const int F4 = 2048 * 512 / 4;
      const int M4 = 4096 * 1024 / 4;
      int i = (uu - 356) * 256 + tid;
      int stride = 3072 * 256;
      for (; i < 2 * F4 + M4; i += stride) {
        const float* s3; unsigned* dst; int k;
        if (i < F4)          { s3 = Whf; dst = (unsigned*)w8f; k = i; }
        else if (i < 2 * F4) { s3 = Whr; dst = (unsigned*)w8r; k = i - F4; }
        else                 { s3 = Whm; dst = (unsigned*)w8m; k = i - 2 * F4; }
        float4 f = ((const float4*)s3)[k];
        unsigned w3 = pk2<false>(f.x, f.y, 0);
        w3 = pk2<true>(f.z, f.w, w3);
        dst[k] = w3;
      }
    }
  }
  phase_barrier(&bar[0]);

  // ================= phase 1: lstm (exact R3 structure) ====================
  {
    int role, c, s;
    if (blk < 512)      { role = 2; c = blk >> 6; s = blk & 63; }
    else if (blk < 640) { int l = blk - 512; role = 0; c = l >> 4; s = l & 15; }
    else                { int l = blk - 640; role = 1; c = l >> 4; s = l & 15; }

    const float* E  = role == 0 ? Ef  : role == 1 ? Er  : Em;
    const u8*    w8 = role == 0 ? w8f : role == 1 ? w8r : w8m;
    u8* hall        = role == 0 ? fwd_all : role == 1 ? rev_all : y_all;
    const int* tokg = (role == 2) ? tok_y : tok_x;
    const int b0 = c * 32;
    int dom0, h0;
    if (role == 2)      { dom0 = c * 64;       h0 = s * 16; }
    else if (role == 0) { dom0 = 512 + c * 16; h0 = s * 32; }
    else                { dom0 = 640 + c * 16; h0 = s * 32; }

    for (int i = tid; i < 34 * 32; i += 256) {
      int t2 = i >> 5, m = i & 31;
      int tk = tokg[t2 * 256 + b0 + m];
      tok_small[i] = (u8)(tk < 0 ? 66 : tk);
    }
    __syncthreads();

    if (role == 2)
      run_lstm16<1024, 64>(w8, E, hall, b0, h0, flags, dom0, s, alds, hT, tok_small);
    else
      run_lstm32<512, 16>(w8, E, role == 1, hall, b0, h0, flags, dom0, s, alds, hT,
                          tok_small);
  }
  phase_barrier(&bar[32]);

  // ================= phase 2: head (272 units) =============================
  if (blk < 272) {
    u8* wq = smem;   // 160*264 = 42240 B
    const int lane = tid & 63, wave = tid >> 6;
    const int lo = lane & 15, q = lane >> 4;
    bool yside = (blk >= 136);
    int mb = yside ? blk - 136 : blk;
    int ij = mb >> 2;
    int bbase = (mb & 3) * 64;

    f32x4 acc[10];
#pragma unroll
    for (int nn = 0; nn < 10; ++nn) acc[nn] = (f32x4){0.f,0.f,0.f,0.f};

    for (int qk = 0; qk < 4; ++qk) {
      long aA[8];
      {
        int row = bbase + wave * 16 + lo;
        const u8* ab;
        if (yside)
          ab = y_all + ((size_t)(ij + 1) * 256 + row) * 1024 + qk * 256 + q * 8;
        else if (qk < 2)
          ab = fwd_all + ((size_t)(ij + 1) * 256 + row) * 512 + qk * 256 + q * 8;
        else
          ab = rev_all + ((size_t)(34 - ij) * 256 + row) * 512 + (qk - 2) * 256 + q * 8;
#pragma unroll
        for (int ki = 0; ki < 8; ++ki) aA[ki] = *(const long*)(ab + ki * 32);
      }

      __syncthreads();
      for (int c8 = tid; c8 < 160 * 32; c8 += 256) {
        int row = c8 >> 5, col = (c8 & 31) << 3;
        *(long*)&wq[row * 264 + col] =
            *(const long*)&Wcat[(size_t)row * 1024 + qk * 256 + col];
      }
      __syncthreads();

#pragma unroll
      for (int ki = 0; ki < 8; ++ki) {
#pragma unroll
        for (int nn = 0; nn < 10; ++nn) {
          long bfv = *(const long*)&wq[(nn * 16 + lo) * 264 + ki * 32 + q * 8];
          acc[nn] = mfma_fp8(aA[ki], bfv, acc[nn]);
        }
      }
    }

#pragma unroll
    for (int nn = 0; nn < 10; ++nn) {
      bool is_sub = (nn < 5);
      int n = (is_sub ? nn : nn - 5) * 16 + lo;
      float bias = 0.0f;
      if (yside && n < 65) bias = is_sub ? b_sub[n] : b_ins[n];
      float* dst = yside ? (is_sub ? ly_sub : ly_ins) : (is_sub ? lx_sub : lx_ins);
#pragma unroll
      for (int r = 0; r < 4; ++r) {
        int b = bbase + wave * 16 + q * 4 + r;
        dst[((size_t)ij * 256 + b) * OP_ + n] = acc[nn][r] + bias;
      }
    }
  }
  phase_barrier(&bar[64]);

  // ================= phase 3: pair (272 units, two-pass LSE) ===============
  if (blk < 272) {
    const int hsel = blk >= 136;
    const int rem = hsel ? blk - 136 : blk;
    const int i = rem >> 2;
    const int bc = rem & 3;
    const int jq = tid >> 6;
    const int bl = tid & 63;
    const int b = bc * 64 + bl;
    const size_t CH = (size_t)SX_ * SY_ * B_;
    const float* lx = hsel ? lx_ins : lx_sub;
    const float* ly = hsel ? ly_ins : ly_sub;
    float* outA = out + (hsel ? 0 : CH);
    float* outB = out + (hsel ? 2 * CH : 3 * CH);

    float4 X[17];
    {
      const float4* ps = (const float4*)(lx + ((size_t)i * 256 + b) * OP_);
#pragma unroll
      for (int qx = 0; qx < 17; ++qx) X[qx] = ps[qx];
    }
    int tx = tok_x[i * 256 + b];

    for (int j = jq; j < 34; j += 4) {
      size_t obase = ((size_t)i * SY_ + j) * 256 + b;
      bool dead = (j == SY_ - 1) || (tx < 0);
      if (!dead) {
        int ty = tok_y[j * 256 + b];
        if (ty < 0) dead = true;
      }
      if (dead) {
        outA[obase] = BIG_NEG;
        outB[obase] = BIG_NEG;
        continue;
      }
      int tn = tok_y[(j + 1) * 256 + b];
      bool ins_ok = (tn != 65);
      int sym = (tn >= 0 && tn < 64) ? tn : -1;

      const float4* py4 = (const float4*)(ly + ((size_t)j * 256 + b) * OP_);
      // pass 1: max over o in [0,65)
      float m = -3.0e38f;
#pragma unroll
      for (int qx = 0; qx < 16; ++qx) {
        float4 yb = py4[qx];
        float a0 = X[qx].x + yb.x, a1 = X[qx].y + yb.y;
        float a2 = X[qx].z + yb.z, a3 = X[qx].w + yb.w;
        m = fmaxf(m, fmaxf(fmaxf(a0, a1), fmaxf(a2, a3)));
      }
      float v64 = X[16].x + py4[16].x;
      m = fmaxf(m, v64);
      // pass 2: exp-sum + capture vs (o == sym < 64)
      float s = 0.0f, vs = 0.0f;
#pragma unroll
      for (int qx = 0; qx < 16; ++qx) {
        float4 yb = py4[qx];
        float a0 = X[qx].x + yb.x, a1 = X[qx].y + yb.y;
        float a2 = X[qx].z + yb.z, a3 = X[qx].w + yb.w;
        s += __expf(a0 - m) + __expf(a1 - m) + __expf(a2 - m) + __expf(a3 - m);
        int o0 = 4 * qx;
        vs = (o0     == sym) ? a0 : vs;
        vs = (o0 + 1 == sym) ? a1 : vs;
        vs = (o0 + 2 == sym) ? a2 : vs;
        vs = (o0 + 3 == sym) ? a3 : vs;
      }
      s += __expf(v64 - m);
      float logZ = m + __logf(s);

      float valB = v64 - logZ;
      float valA = (sym >= 0) ? (vs - logZ) : 0.0f;
      outA[obase] = ins_ok ? valA : BIG_NEG;
      outB[obase] = valB;
    }
  }
}

// ---------------------------------------------------------------------------
// launch: memset (flags + barrier counters) + ONE fused kernel
// ---------------------------------------------------------------------------
extern "C" void kernel_launch(void* const* d_in, const int* in_sizes, int n_in,
                              void* d_out, int out_size, void* d_ws, size_t ws_size,
                              hipStream_t stream) {
  const float* sources = (const float*)d_in[0];
  const float* targets = (const float*)d_in[1];
  const float* Wih_f = (const float*)d_in[2];
  const float* Whh_f = (const float*)d_in[3];
  const float* b_f   = (const float*)d_in[4];
  const float* Wih_r = (const float*)d_in[5];
  const float* Whh_r = (const float*)d_in[6];
  const float* b_r   = (const float*)d_in[7];
  const float* Wih_m = (const float*)d_in[8];
  const float* Whh_m = (const float*)d_in[9];
  const float* b_m   = (const float*)d_in[10];
  const float* W_sub = (const float*)d_in[11];
  const float* b_sub = (const float*)d_in[12];
  const float* W_ins = (const float*)d_in[13];
  const float* b_ins = (const float*)d_in[14];
  float* out = (float*)d_out;

  char* w = (char*)d_ws;
  // flags: 768 producer slots x 128B  +  3 barrier counters x 128B
  constexpr size_t FLAG_SZ = (size_t)(768 * 32 + 3 * 32) * 4;
  constexpr size_t TOK_SZ  = (size_t)SX_ * B_ * 4;
  constexpr size_t WCAT_SZ = (size_t)160 * 1024;            // head W fp8
  constexpr size_t W8F_SZ  = (size_t)2048 * 512;            // fwd Whh fp8
  constexpr size_t W8M_SZ  = (size_t)4096 * 1024;           // mod Whh fp8
  constexpr size_t EF_SZ   = (size_t)67 * 2048 * 4;         // E tables f32
  constexpr size_t EM_SZ   = (size_t)67 * 4096 * 4;
  constexpr size_t LX_SZ   = (size_t)SX_ * B_ * OP_ * 4;
  constexpr size_t HF_SZ   = (size_t)35 * B_ * 512;         // h slabs fp8
  constexpr size_t HM_SZ   = (size_t)35 * B_ * 1024;

  size_t off = 0;
  unsigned* flags = (unsigned*)(w + off); off += FLAG_SZ;
  int*  tok_x   = (int*)(w + off);  off += TOK_SZ;
  int*  tok_y   = (int*)(w + off);  off += TOK_SZ;
  off = (off + 255) & ~(size_t)255;
  u8*   Wcat    = (u8*)(w + off);   off += WCAT_SZ;
  u8*   w8_f    = (u8*)(w + off);   off += W8F_SZ;
  u8*   w8_r    = (u8*)(w + off);   off += W8F_SZ;
  u8*   w8_m    = (u8*)(w + off);   off += W8M_SZ;
  float* E_f    = (float*)(w + off); off += EF_SZ;
  float* E_r    = (float*)(w + off); off += EF_SZ;
  float* E_m    = (float*)(w + off); off += EM_SZ;
  float* lx_sub = (float*)(w + off); off += LX_SZ;
  float* lx_ins = (float*)(w + off); off += LX_SZ;
  float* ly_sub = (float*)(w + off); off += LX_SZ;
  float* ly_ins = (float*)(w + off); off += LX_SZ;
  u8* fwd_all   = (u8*)(w + off);   off += HF_SZ;
  u8* rev_all   = (u8*)(w + off);   off += HF_SZ;
  u8* y_all     = (u8*)(w + off);   off += HM_SZ;
  (void)ws_size; (void)in_sizes; (void)n_in; (void)out_size;

  (void)hipMemsetAsync(flags, 0, FLAG_SZ, stream);

  fused_all<<<NBLK, 256, 0, stream>>>(
      sources, targets, tok_x, tok_y,
      W_sub, W_ins, Wcat,
      Wih_f, b_f, Wih_r, b_r, Wih_m, b_m, E_f, E_r, E_m,
      Whh_f, Whh_r, Whh_m, w8_f, w8_r, w8_m,
      b_sub, b_ins, lx_sub, lx_ins, ly_sub, ly_ins,
      fwd_all, rev_all, y_all, out, flags);
}

// Round 9
// 359.436 us; speedup vs baseline: 1.6727x; 1.6727x over previous
//
#include <hip/hip_runtime.h>

typedef __attribute__((ext_vector_type(4))) float f32x4;
typedef unsigned char u8;
typedef unsigned long long u64t;

#define BIG_NEG -1000000000.0f

static constexpr int B_  = 256;
static constexpr int SX_ = 34;
static constexpr int SY_ = 34;
static constexpr int IND = 66;   // IN_DIM
static constexpr int OP_ = 80;   // padded OUT_DIM (65 -> 80)

__device__ __forceinline__ f32x4 mfma_fp8(long a, long b, f32x4 c) {
  return __builtin_amdgcn_mfma_f32_16x16x32_fp8_fp8(a, b, c, 0, 0, 0);
}
__device__ __forceinline__ float sigm(float x)  { return 1.0f / (1.0f + __expf(-x)); }
__device__ __forceinline__ float tanhx(float x) { return 2.0f * sigm(2.0f * x) - 1.0f; }
template <bool HI>
__device__ __forceinline__ unsigned pk2(float a, float b, unsigned old) {
  return __builtin_amdgcn_cvt_pk_fp8_f32(a, b, (int)old, HI);
}
// select element j (runtime 0..3) of f32x4 without dynamic indexing
__device__ __forceinline__ float rsel(f32x4 a, int j) {
  float lo = (j & 1) ? a[1] : a[0];
  float hi = (j & 1) ? a[3] : a[2];
  return (j & 2) ? hi : lo;
}

// ---------------------------------------------------------------------------
// fused prep kernel: blocks [0,68) decode | [68,228) pad_head |
// [228,356) build_E | [356,3428) conv_fp8 (grid-stride).
// Blocks [0,97) additionally zero the flag region + barrier counter
// (replaces the hipMemsetAsync dispatch; kernel boundary orders it).
// ---------------------------------------------------------------------------
__global__ __launch_bounds__(256) void prep_all(
    const float* __restrict__ src, const float* __restrict__ tgt,
    int* __restrict__ tok_x, int* __restrict__ tok_y,
    const float* __restrict__ Wsub, const float* __restrict__ Wins,
    u8* __restrict__ Wcat,
    const float* __restrict__ Wihf, const float* __restrict__ bf,
    const float* __restrict__ Wihr, const float* __restrict__ br,
    const float* __restrict__ Wihm, const float* __restrict__ bm,
    float* __restrict__ Ef, float* __restrict__ Er, float* __restrict__ Em,
    const float* __restrict__ Whf, const float* __restrict__ Whr,
    const float* __restrict__ Whm,
    u8* __restrict__ w8f, u8* __restrict__ w8r, u8* __restrict__ w8m,
    unsigned* __restrict__ flagsz) {
  __shared__ float tile[64 * 67];
  const int blk = blockIdx.x;
  const int tid = threadIdx.x;

  // zero flags (768*32 u32 = 96 blocks x 256) + barrier counter
  if (blk < 96)      flagsz[blk * 256 + tid] = 0;
  else if (blk == 96 && tid == 0) flagsz[768 * 32] = 0;

  if (blk < 68) {                       // ---- decode tokens ----
    int idx = blk * 256 + tid;
    const int half = SX_ * B_;
    const float* base = (idx < half) ? src : tgt;
    int* outp         = (idx < half) ? tok_x : tok_y;
    int k = (idx < half) ? idx : idx - half;
    const float* p = base + (size_t)k * IND;
    int tok = -1;
    for (int v = 0; v < IND; ++v) if (p[v] > 0.5f) tok = v;
    outp[k] = tok;
  } else if (blk < 228) {               // ---- pad head W -> fp8 ----
    int widx = (blk - 68) * 256 + tid;
    int row = widx >> 8;
    int wc  = widx & 255;
    int srow = row < 80 ? row : row - 80;
    const float* W = row < 80 ? Wsub : Wins;
    float f0 = 0.f, f1 = 0.f, f2 = 0.f, f3 = 0.f;
    if (srow < 65) {
      const float* p = W + (size_t)srow * 1024 + wc * 4;
      f0 = p[0]; f1 = p[1]; f2 = p[2]; f3 = p[3];
    }
    unsigned w = pk2<false>(f0, f1, 0);
    w = pk2<true>(f2, f3, w);
    ((unsigned*)Wcat)[widx] = w;
  } else if (blk < 356) {               // ---- build E (LDS transpose) ----
    int tb = blk - 228;
    const float* W; const float* bias; float* E; int H4; int n0;
    if (tb < 32)      { W = Wihf; bias = bf; E = Ef; H4 = 2048; n0 = tb * 64; }
    else if (tb < 64) { W = Wihr; bias = br; E = Er; H4 = 2048; n0 = (tb - 32) * 64; }
    else              { W = Wihm; bias = bm; E = Em; H4 = 4096; n0 = (tb - 64) * 64; }
    const float* s2 = W + (size_t)n0 * IND;
    for (int i = tid; i < 64 * IND; i += 256) {
      int n = i / IND, v = i - n * IND;
      tile[n * 67 + v] = s2[i];
    }
    __syncthreads();
    int lane = tid & 63, w2 = tid >> 6;
    float bl = bias[n0 + lane];
    for (int v = w2; v < 67; v += 4) {
      float val = (v < 66 ? tile[lane * 67 + v] : 0.f) + bl;
      E[(size_t)v * H4 + n0 + lane] = val;
    }
  } else {                              // ---- conv Whh -> fp8 ----
    const int F4 = 2048 * 512 / 4;
    const int M4 = 4096 * 1024 / 4;
    int i = (blk - 356) * 256 + tid;
    int stride = 3072 * 256;
    for (; i < 2 * F4 + M4; i += stride) {
      const float* s3; unsigned* dst; int k;
      if (i < F4)          { s3 = Whf; dst = (unsigned*)w8f; k = i; }
      else if (i < 2 * F4) { s3 = Whr; dst = (unsigned*)w8r; k = i - F4; }
      else                 { s3 = Whm; dst = (unsigned*)w8m; k = i - 2 * F4; }
      float4 f = ((const float4*)s3)[k];
      unsigned w3 = pk2<false>(f.x, f.y, 0);
      w3 = pk2<true>(f.z, f.w, w3);
      dst[k] = w3;
    }
  }
}

// ---------------------------------------------------------------------------
// persistent LSTM, 768 blocks x 256 thr, 3 blocks/CU — EXACT R3 structure
// (best measured: 192 us). mod: 512 blocks (32b x 16u); fwd/rev: 128+128
// (32b x 32u). Flag protocol: store h (relaxed agent atomics) -> vmcnt(0)
// -> syncthreads -> fire flag; consumer polls flags then stages with 8B
// relaxed agent atomic loads (LLC-direct), AST = HH+8.
// ---------------------------------------------------------------------------
template <int HH, int NS>
__device__ __forceinline__ void run_lstm32(
    const u8* __restrict__ w8, const float* __restrict__ E,
    bool revr, u8* __restrict__ hall, int b0, int h0,
    unsigned* __restrict__ flags, int dom0, int myid,
    u8* __restrict__ alds, u8* __restrict__ hT, const u8* __restrict__ tok_small) {
  const int tid = threadIdx.x;
  const int lane = tid & 63, w = tid >> 6;
  const int lo = lane & 15, q = lane >> 4;
  constexpr int AST = HH + 8;
  constexpr int U8C = HH / 8;
  constexpr int USH = (HH == 1024) ? 7 : 6;
  constexpr int NI  = (32 * U8C) / 256;   // 8 for HH=512
  constexpr int NK  = HH / 32;
  const int hh = lo & 7;
  const bool hi = (lo >= 8);
  const int hu_e = h0 + w * 8 + hh;

  long breg0[NK], breg1[NK];
  {
    const u8* brow0 = w8 + (size_t)((lo >> 3) * HH + hu_e) * HH + q * 8;
    const u8* brow1 = w8 + (size_t)((2 + (lo >> 3)) * HH + hu_e) * HH + q * 8;
#pragma unroll
    for (int kk = 0; kk < NK; ++kk) {
      breg0[kk] = *(const long*)(brow0 + kk * 32);
      breg1[kk] = *(const long*)(brow1 + kk * 32);
    }
  }
  float creg[4] = {0.f, 0.f, 0.f, 0.f};

  for (int t = 0; t < 34; ++t) {
    const int tpos = revr ? 33 - t : t;
    const u8* tkp = tok_small + tpos * 32;

    // hoisted E-gather (issues before poll; latency hides under it)
    float ev[2][4][2];
#pragma unroll
    for (int mt = 0; mt < 2; ++mt)
#pragma unroll
      for (int rr = 0; rr < 2; ++rr) {
        int r = (hi ? 2 : 0) + rr;
        int v = tkp[mt * 16 + q * 4 + r];
        const float* e = E + (size_t)v * (4 * HH) + hu_e;
        ev[mt][0][rr] = e[0];
        ev[mt][1][rr] = e[HH];
        ev[mt][2][rr] = e[2 * HH];
        ev[mt][3][rr] = e[3 * HH];
      }

    f32x4 acc[2][2];
#pragma unroll
    for (int mt = 0; mt < 2; ++mt) {
      acc[mt][0] = (f32x4){0.f, 0.f, 0.f, 0.f};
      acc[mt][1] = (f32x4){0.f, 0.f, 0.f, 0.f};
    }

    if (t > 0) {
      if (tid < NS) {
        const unsigned tgt = (unsigned)t;
        int spin = 0;
        for (;;) {
          unsigned v = __hip_atomic_load(&flags[(dom0 + tid) * 32],
                                         __ATOMIC_RELAXED, __HIP_MEMORY_SCOPE_AGENT);
          if (__ballot(v < tgt) == 0) break;
          __builtin_amdgcn_s_sleep(1);
          if (++spin > (1 << 17)) break;
        }
      }
      __syncthreads();

      const u8* hsrc = hall + (size_t)t * (256 * HH);
      u64t tmp[NI];
#pragma unroll
      for (int ii = 0; ii < NI; ++ii) {
        int idx = tid + ii * 256;
        tmp[ii] = __hip_atomic_load(
            (const u64t*)(hsrc + (size_t)(b0 + (idx >> USH)) * HH + (idx & (U8C - 1)) * 8),
            __ATOMIC_RELAXED, __HIP_MEMORY_SCOPE_AGENT);
      }
#pragma unroll
      for (int ii = 0; ii < NI; ++ii) {
        int idx = tid + ii * 256;
        *(u64t*)&alds[(idx >> USH) * AST + (idx & (U8C - 1)) * 8] = tmp[ii];
      }
      __syncthreads();

      const u8* a0p = alds + lo * AST + q * 8;
      const u8* a1p = alds + (16 + lo) * AST + q * 8;
#pragma unroll
      for (int kk = 0; kk < NK; ++kk) {
        long a0 = *(const long*)(a0p + kk * 32);
        long a1 = *(const long*)(a1p + kk * 32);
        acc[0][0] = mfma_fp8(a0, breg0[kk], acc[0][0]);
        acc[0][1] = mfma_fp8(a0, breg1[kk], acc[0][1]);
        acc[1][0] = mfma_fp8(a1, breg0[kk], acc[1][0]);
        acc[1][1] = mfma_fp8(a1, breg1[kk], acc[1][1]);
      }
    }

#pragma unroll
    for (int mt = 0; mt < 2; ++mt) {
      f32x4 t0 = acc[mt][0], t1 = acc[mt][1];
      f32x4 p0, p1;
#pragma unroll
      for (int c2 = 0; c2 < 4; ++c2) {
        p0[c2] = __shfl_xor(t0[c2], 8, 64);
        p1[c2] = __shfl_xor(t1[c2], 8, 64);
      }
#pragma unroll
      for (int rr = 0; rr < 2; ++rr) {
        int r = (hi ? 2 : 0) + rr;
        float iv = (hi ? p0[r] : t0[r]) + ev[mt][0][rr];
        float fv = (hi ? t0[r] : p0[r]) + ev[mt][1][rr];
        float gv = (hi ? p1[r] : t1[r]) + ev[mt][2][rr];
        float ov = (hi ? t1[r] : p1[r]) + ev[mt][3][rr];
        int m = mt * 16 + q * 4 + r;
        float cold = creg[mt * 2 + rr];
        float cn = sigm(fv) * cold + sigm(iv) * tanhx(gv);
        float hn = sigm(ov) * tanhx(cn);
        creg[mt * 2 + rr] = cn;
        hT[m * 32 + w * 8 + hh] = (u8)(pk2<false>(hn, hn, 0) & 0xffu);
      }
    }
    __syncthreads();

    {
      int m = tid >> 3, cc = tid & 7;
      unsigned val = *(const unsigned*)&hT[m * 32 + cc * 4];
      u8* hdst = hall + (size_t)(t + 1) * (256 * HH);
      __hip_atomic_store((unsigned*)(hdst + (size_t)(b0 + m) * HH + h0 + cc * 4),
                         val, __ATOMIC_RELAXED, __HIP_MEMORY_SCOPE_AGENT);
    }
    if (t < 33) {
      __asm__ volatile("s_waitcnt vmcnt(0)" ::: "memory");
      __syncthreads();
      if (tid == 0)
        __hip_atomic_store(&flags[(dom0 + myid) * 32], (unsigned)(t + 1),
                           __ATOMIC_RELAXED, __HIP_MEMORY_SCOPE_AGENT);
    }
  }
}

template <int HH, int NS>
__device__ __forceinline__ void run_lstm16(
    const u8* __restrict__ w8, const float* __restrict__ E,
    u8* __restrict__ hall, int b0, int h0,
    unsigned* __restrict__ flags, int dom0, int myid,
    u8* __restrict__ alds, u8* __restrict__ hT, const u8* __restrict__ tok_small) {
  const int tid = threadIdx.x;
  const int lane = tid & 63, w = tid >> 6;
  const int lo = lane & 15, q = lane >> 4;
  constexpr int AST = HH + 8;
  constexpr int U8C = HH / 8;          // 128
  constexpr int USH = 7;               // HH = 1024
  constexpr int NI  = (32 * U8C) / 256;   // 16
  constexpr int NK  = HH / 32;         // 32
  const int g = lo & 3;
  const int u = lo >> 2;
  const int hu = h0 + w * 4 + u;

  long breg[NK];
  {
    const u8* brow = w8 + (size_t)(g * HH + hu) * HH + q * 8;
#pragma unroll
    for (int kk = 0; kk < NK; ++kk) breg[kk] = *(const long*)(brow + kk * 32);
  }
  float creg[2] = {0.f, 0.f};

  for (int t = 0; t < 34; ++t) {
    const u8* tkp = tok_small + t * 32;

    float ev[2][4];
#pragma unroll
    for (int mt = 0; mt < 2; ++mt) {
      int v = tkp[mt * 16 + q * 4 + g];
      const float* e = E + (size_t)v * (4 * HH) + hu;
      ev[mt][0] = e[0]; ev[mt][1] = e[HH]; ev[mt][2] = e[2 * HH]; ev[mt][3] = e[3 * HH];
    }

    f32x4 acc[2];
    acc[0] = (f32x4){0.f, 0.f, 0.f, 0.f};
    acc[1] = (f32x4){0.f, 0.f, 0.f, 0.f};

    if (t > 0) {
      if (tid < NS) {
        const unsigned tgt = (unsigned)t;
        int spin = 0;
        for (;;) {
          unsigned v = __hip_atomic_load(&flags[(dom0 + tid) * 32],
                                         __ATOMIC_RELAXED, __HIP_MEMORY_SCOPE_AGENT);
          if (__ballot(v < tgt) == 0) break;
          __builtin_amdgcn_s_sleep(1);
          if (++spin > (1 << 17)) break;
        }
      }
      __syncthreads();

      const u8* hsrc = hall + (size_t)t * (256 * HH);
      u64t tmp[NI];
#pragma unroll
      for (int ii = 0; ii < NI; ++ii) {
        int idx = tid + ii * 256;
        tmp[ii] = __hip_atomic_load(
            (const u64t*)(hsrc + (size_t)(b0 + (idx >> USH)) * HH + (idx & (U8C - 1)) * 8),
            __ATOMIC_RELAXED, __HIP_MEMORY_SCOPE_AGENT);
      }
#pragma unroll
      for (int ii = 0; ii < NI; ++ii) {
        int idx = tid + ii * 256;
        *(u64t*)&alds[(idx >> USH) * AST + (idx & (U8C - 1)) * 8] = tmp[ii];
      }
      __syncthreads();

      const u8* a0p = alds + lo * AST + q * 8;
      const u8* a1p = alds + (16 + lo) * AST + q * 8;
#pragma unroll
      for (int kk = 0; kk < NK; ++kk) {
        long a0 = *(const long*)(a0p + kk * 32);
        long a1 = *(const long*)(a1p + kk * 32);
        acc[0] = mfma_fp8(a0, breg[kk], acc[0]);
        acc[1] = mfma_fp8(a1, breg[kk], acc[1]);
      }
    }

#pragma unroll
    for (int mt = 0; mt < 2; ++mt) {
      f32x4 a = acc[mt];
      float own = rsel(a, g);
      float y1  = __shfl_xor(rsel(a, g ^ 1), 1, 64);
      float y2  = __shfl_xor(rsel(a, g ^ 2), 2, 64);
      float y3  = __shfl_xor(rsel(a, g ^ 3), 3, 64);
      float iv = (g == 0) ? own : (g == 1) ? y1 : (g == 2) ? y2 : y3;
      float fv = (g == 0) ? y1 : (g == 1) ? own : (g == 2) ? y3 : y2;
      float gv = (g == 0) ? y2 : (g == 1) ? y3 : (g == 2) ? own : y1;
      float ov = (g == 0) ? y3 : (g == 1) ? y2 : (g == 2) ? y1 : own;
      iv += ev[mt][0]; fv += ev[mt][1]; gv += ev[mt][2]; ov += ev[mt][3];
      int m = mt * 16 + q * 4 + g;
      float cold = creg[mt];
      float cn = sigm(fv) * cold + sigm(iv) * tanhx(gv);
      float hn = sigm(ov) * tanhx(cn);
      creg[mt] = cn;
      hT[m * 16 + w * 4 + u] = (u8)(pk2<false>(hn, hn, 0) & 0xffu);
    }
    __syncthreads();

    if (tid < 128) {
      int m = tid >> 2, cc = tid & 3;
      unsigned val = *(const unsigned*)&hT[m * 16 + cc * 4];
      u8* hdst = hall + (size_t)(t + 1) * (256 * HH);
      __hip_atomic_store((unsigned*)(hdst + (size_t)(b0 + m) * HH + h0 + cc * 4),
                         val, __ATOMIC_RELAXED, __HIP_MEMORY_SCOPE_AGENT);
    }
    if (t < 33) {
      __asm__ volatile("s_waitcnt vmcnt(0)" ::: "memory");
      __syncthreads();
      if (tid == 0)
        __hip_atomic_store(&flags[(dom0 + myid) * 32], (unsigned)(t + 1),
                           __ATOMIC_RELAXED, __HIP_MEMORY_SCOPE_AGENT);
    }
  }
}

__global__ __launch_bounds__(256, 3) void lstm_persist(
    const int* __restrict__ tok_x, const int* __restrict__ tok_y,
    const float* __restrict__ E_f, const u8* __restrict__ w8_f,
    const float* __restrict__ E_r, const u8* __restrict__ w8_r,
    const float* __restrict__ E_m, const u8* __restrict__ w8_m,
    u8* __restrict__ fwd_all, u8* __restrict__ rev_all, u8* __restrict__ y_all,
    unsigned* __restrict__ flags) {
  __shared__ u8 alds[32 * 1032] __attribute__((aligned(16)));  // 33 KB stage
  __shared__ u8 hT[32 * 32] __attribute__((aligned(16)));      // transpose buf
  __shared__ u8 tok_small[34 * 32];    // this block's tokens (66 = none)

  const int b = blockIdx.x;
  int role, c, s;
  if (b < 512)      { role = 2; c = b >> 6; s = b & 63; }
  else if (b < 640) { int l = b - 512; role = 0; c = l >> 4; s = l & 15; }
  else              { int l = b - 640; role = 1; c = l >> 4; s = l & 15; }

  const float* E  = role == 0 ? E_f  : role == 1 ? E_r  : E_m;
  const u8*    w8 = role == 0 ? w8_f : role == 1 ? w8_r : w8_m;
  u8* hall        = role == 0 ? fwd_all : role == 1 ? rev_all : y_all;
  const int* tokg = (role == 2) ? tok_y : tok_x;
  const int b0 = c * 32;
  int dom0, h0;
  if (role == 2)      { dom0 = c * 64;       h0 = s * 16; }
  else if (role == 0) { dom0 = 512 + c * 16; h0 = s * 32; }
  else                { dom0 = 640 + c * 16; h0 = s * 32; }

  for (int i = threadIdx.x; i < 34 * 32; i += 256) {
    int t2 = i >> 5, m = i & 31;
    int tk = tokg[t2 * 256 + b0 + m];
    tok_small[i] = (u8)(tk < 0 ? 66 : tk);
  }
  __syncthreads();

  if (role == 2)
    run_lstm16<1024, 64>(w8, E, hall, b0, h0, flags, dom0, s, alds, hT, tok_small);
  else
    run_lstm32<512, 16>(w8, E, role == 1, hall, b0, h0, flags, dom0, s, alds, hT,
                        tok_small);
}

// ---------------------------------------------------------------------------
// headpair: fused head + pair, 272 blocks x 256 thr, __launch_bounds__(256,2)
// (42.2 KB LDS -> 2 blocks/CU guaranteed -> all 272 resident -> barrier safe).
// head phase writes lx/ly via relaxed AGENT-scope atomic 4B stores (LLC-
// direct, no release fence needed) -> vmcnt(0) -> relaxed fetch_add barrier
// -> per-block ACQUIRE invalidate (cheap, no writeback) -> pair phase reads
// lx/ly with plain cached loads.  Two-pass LSE (R4-validated) keeps VGPR
// under the (256,2) cap.
// ---------------------------------------------------------------------------
__global__ __launch_bounds__(256, 2) void headpair(
    const u8* __restrict__ fwd_all, const u8* __restrict__ rev_all,
    const u8* __restrict__ y_all, const u8* __restrict__ Wcat,
    const float* __restrict__ b_sub, const float* __restrict__ b_ins,
    float* __restrict__ lx_sub, float* __restrict__ lx_ins,
    float* __restrict__ ly_sub, float* __restrict__ ly_ins,
    const int* __restrict__ tok_x, const int* __restrict__ tok_y,
    float* __restrict__ out, unsigned* __restrict__ bar) {
  __shared__ u8 wq[160 * 264];   // 42240 B, row pad 264 for bank spread
  const int tid = threadIdx.x;
  const int lane = tid & 63, wave = tid >> 6;
  const int lo = lane & 15, q = lane >> 4;
  const int blk = blockIdx.x;

  // ===================== phase 1: head =====================
  {
    bool yside = (blk >= 136);
    int mb = yside ? blk - 136 : blk;
    int ij = mb >> 2;
    int bbase = (mb & 3) * 64;

    f32x4 acc[10];
#pragma unroll
    for (int nn = 0; nn < 10; ++nn) acc[nn] = (f32x4){0.f,0.f,0.f,0.f};

    for (int qk = 0; qk < 4; ++qk) {
      long aA[8];
      {
        int row = bbase + wave * 16 + lo;
        const u8* ab;
        if (yside)
          ab = y_all + ((size_t)(ij + 1) * 256 + row) * 1024 + qk * 256 + q * 8;
        else if (qk < 2)
          ab = fwd_all + ((size_t)(ij + 1) * 256 + row) * 512 + qk * 256 + q * 8;
        else
          ab = rev_all + ((size_t)(34 - ij) * 256 + row) * 512 + (qk - 2) * 256 + q * 8;
#pragma unroll
        for (int ki = 0; ki < 8; ++ki) aA[ki] = *(const long*)(ab + ki * 32);
      }

      for (int c8 = tid; c8 < 160 * 32; c8 += 256) {
        int row = c8 >> 5, col = (c8 & 31) << 3;
        *(long*)&wq[row * 264 + col] =
            *(const long*)&Wcat[(size_t)row * 1024 + qk * 256 + col];
      }
      __syncthreads();

#pragma unroll
      for (int ki = 0; ki < 8; ++ki) {
#pragma unroll
        for (int nn = 0; nn < 10; ++nn) {
          long bfv = *(const long*)&wq[(nn * 16 + lo) * 264 + ki * 32 + q * 8];
          acc[nn] = mfma_fp8(aA[ki], bfv, acc[nn]);
        }
      }
      __syncthreads();
    }

#pragma unroll
    for (int nn = 0; nn < 10; ++nn) {
      bool is_sub = (nn < 5);
      int n = (is_sub ? nn : nn - 5) * 16 + lo;
      float bias = 0.0f;
      if (yside && n < 65) bias = is_sub ? b_sub[n] : b_ins[n];
      float* dst = yside ? (is_sub ? ly_sub : ly_ins) : (is_sub ? lx_sub : lx_ins);
#pragma unroll
      for (int r = 0; r < 4; ++r) {
        int b = bbase + wave * 16 + q * 4 + r;
        // LLC-direct atomic store: visible to all XCDs after vmcnt drain
        __hip_atomic_store(
            (unsigned*)&dst[((size_t)ij * 256 + b) * OP_ + n],
            __float_as_uint(acc[nn][r] + bias),
            __ATOMIC_RELAXED, __HIP_MEMORY_SCOPE_AGENT);
      }
    }
  }

  // ===================== barrier (lstm-proven protocol) =====================
  __asm__ volatile("s_waitcnt vmcnt(0)" ::: "memory");  // atomic stores at LLC
  __syncthreads();
  if (tid == 0) {
    __hip_atomic_fetch_add(bar, 1u, __ATOMIC_RELAXED, __HIP_MEMORY_SCOPE_AGENT);
    int spin = 0;
    for (;;) {
      unsigned v = __hip_atomic_load(bar, __ATOMIC_RELAXED, __HIP_MEMORY_SCOPE_AGENT);
      if (v >= 272u) break;
      __builtin_amdgcn_s_sleep(2);
      if (++spin > (1 << 20)) break;   // safety exit
    }
  }
  __syncthreads();
  // invalidate L1/L2 so plain loads cannot hit stale prior-replay lines
  __builtin_amdgcn_fence(__ATOMIC_ACQUIRE, "agent");
  __syncthreads();

  // ===================== phase 2: pair (two-pass LSE) =====================
  {
    const int hsel = blk >= 136;
    const int rem = hsel ? blk - 136 : blk;
    const int i = rem >> 2;
    const int bc = rem & 3;
    const int jq = tid >> 6;
    const int bl = tid & 63;
    const int b = bc * 64 + bl;
    const size_t CH = (size_t)SX_ * SY_ * B_;
    const float* lx = hsel ? lx_ins : lx_sub;
    const float* ly = hsel ? ly_ins : ly_sub;
    float* outA = out + (hsel ? 0 : CH);
    float* outB = out + (hsel ? 2 * CH : 3 * CH);

    float4 X[17];
    {
      const float4* ps = (const float4*)(lx + ((size_t)i * 256 + b) * OP_);
#pragma unroll
      for (int qx = 0; qx < 17; ++qx) X[qx] = ps[qx];
    }
    int tx = tok_x[i * 256 + b];

    for (int j = jq; j < 34; j += 4) {
      size_t obase = ((size_t)i * SY_ + j) * 256 + b;
      bool dead = (j == SY_ - 1) || (tx < 0);
      if (!dead) {
        int ty = tok_y[j * 256 + b];
        if (ty < 0) dead = true;
      }
      if (dead) {
        outA[obase] = BIG_NEG;
        outB[obase] = BIG_NEG;
        continue;
      }
      int tn = tok_y[(j + 1) * 256 + b];
      bool ins_ok = (tn != 65);
      int sym = (tn >= 0 && tn < 64) ? tn : -1;

      const float4* py4 = (const float4*)(ly + ((size_t)j * 256 + b) * OP_);
      // pass 1: max over o in [0,65)
      float m = -3.0e38f;
#pragma unroll
      for (int qx = 0; qx < 16; ++qx) {
        float4 yb = py4[qx];
        float a0 = X[qx].x + yb.x, a1 = X[qx].y + yb.y;
        float a2 = X[qx].z + yb.z, a3 = X[qx].w + yb.w;
        m = fmaxf(m, fmaxf(fmaxf(a0, a1), fmaxf(a2, a3)));
      }
      float v64 = X[16].x + py4[16].x;
      m = fmaxf(m, v64);
      // pass 2: exp-sum + capture vs (o == sym < 64)
      float s = 0.0f, vs = 0.0f;
#pragma unroll
      for (int qx = 0; qx < 16; ++qx) {
        float4 yb = py4[qx];
        float a0 = X[qx].x + yb.x, a1 = X[qx].y + yb.y;
        float a2 = X[qx].z + yb.z, a3 = X[qx].w + yb.w;
        s += __expf(a0 - m) + __expf(a1 - m) + __expf(a2 - m) + __expf(a3 - m);
        int o0 = 4 * qx;
        vs = (o0     == sym) ? a0 : vs;
        vs = (o0 + 1 == sym) ? a1 : vs;
        vs = (o0 + 2 == sym) ? a2 : vs;
        vs = (o0 + 3 == sym) ? a3 : vs;
      }
      s += __expf(v64 - m);
      float logZ = m + __logf(s);

      float valB = v64 - logZ;                       // del (sub) / end (ins)
      float valA = (sym >= 0) ? (vs - logZ) : 0.0f;  // sub / ins value
      outA[obase] = ins_ok ? valA : BIG_NEG;
      outB[obase] = valB;
    }
  }
}

// ---------------------------------------------------------------------------
// launch: 3 dispatches (prep zeroes flags; no memset node)
// ---------------------------------------------------------------------------
extern "C" void kernel_launch(void* const* d_in, const int* in_sizes, int n_in,
                              void* d_out, int out_size, void* d_ws, size_t ws_size,
                              hipStream_t stream) {
  const float* sources = (const float*)d_in[0];
  const float* targets = (const float*)d_in[1];
  const float* Wih_f = (const float*)d_in[2];
  const float* Whh_f = (const float*)d_in[3];
  const float* b_f   = (const float*)d_in[4];
  const float* Wih_r = (const float*)d_in[5];
  const float* Whh_r = (const float*)d_in[6];
  const float* b_r   = (const float*)d_in[7];
  const float* Wih_m = (const float*)d_in[8];
  const float* Whh_m = (const float*)d_in[9];
  const float* b_m   = (const float*)d_in[10];
  const float* W_sub = (const float*)d_in[11];
  const float* b_sub = (const float*)d_in[12];
  const float* W_ins = (const float*)d_in[13];
  const float* b_ins = (const float*)d_in[14];
  float* out = (float*)d_out;

  char* w = (char*)d_ws;
  // flags: 768 producer slots x 128B + 1 barrier counter (zeroed by prep)
  constexpr size_t FLAG_SZ = (size_t)(768 * 32 + 32) * 4;
  constexpr size_t TOK_SZ  = (size_t)SX_ * B_ * 4;
  constexpr size_t WCAT_SZ = (size_t)160 * 1024;            // head W fp8
  constexpr size_t W8F_SZ  = (size_t)2048 * 512;            // fwd Whh fp8
  constexpr size_t W8M_SZ  = (size_t)4096 * 1024;           // mod Whh fp8
  constexpr size_t EF_SZ   = (size_t)67 * 2048 * 4;         // E tables f32
  constexpr size_t EM_SZ   = (size_t)67 * 4096 * 4;
  constexpr size_t LX_SZ   = (size_t)SX_ * B_ * OP_ * 4;
  constexpr size_t HF_SZ   = (size_t)35 * B_ * 512;         // h slabs fp8
  constexpr size_t HM_SZ   = (size_t)35 * B_ * 1024;

  size_t off = 0;
  unsigned* flags = (unsigned*)(w + off); off += FLAG_SZ;
  int*  tok_x   = (int*)(w + off);  off += TOK_SZ;
  int*  tok_y   = (int*)(w + off);  off += TOK_SZ;
  off = (off + 255) & ~(size_t)255;
  u8*   Wcat    = (u8*)(w + off);   off += WCAT_SZ;
  u8*   w8_f    = (u8*)(w + off);   off += W8F_SZ;
  u8*   w8_r    = (u8*)(w + off);   off += W8F_SZ;
  u8*   w8_m    = (u8*)(w + off);   off += W8M_SZ;
  float* E_f    = (float*)(w + off); off += EF_SZ;
  float* E_r    = (float*)(w + off); off += EF_SZ;
  float* E_m    = (float*)(w + off); off += EM_SZ;
  float* lx_sub = (float*)(w + off); off += LX_SZ;
  float* lx_ins = (float*)(w + off); off += LX_SZ;
  float* ly_sub = (float*)(w + off); off += LX_SZ;
  float* ly_ins = (float*)(w + off); off += LX_SZ;
  u8* fwd_all   = (u8*)(w + off);   off += HF_SZ;
  u8* rev_all   = (u8*)(w + off);   off += HF_SZ;
  u8* y_all     = (u8*)(w + off);   off += HM_SZ;
  (void)ws_size; (void)in_sizes; (void)n_in; (void)out_size;

  prep_all<<<3428, 256, 0, stream>>>(
      sources, targets, tok_x, tok_y,
      W_sub, W_ins, Wcat,
      Wih_f, b_f, Wih_r, b_r, Wih_m, b_m, E_f, E_r, E_m,
      Whh_f, Whh_r, Whh_m, w8_f, w8_r, w8_m, flags);

  lstm_persist<<<768, 256, 0, stream>>>(
      tok_x, tok_y,
      E_f, w8_f,
      E_r, w8_r,
      E_m, w8_m,
      fwd_all, rev_all, y_all, flags);

  headpair<<<272, 256, 0, stream>>>(
      fwd_all, rev_all, y_all, Wcat, b_sub, b_ins,
      lx_sub, lx_ins, ly_sub, ly_ins, tok_x, tok_y, out,
      flags + 768 * 32);
}

// Round 10
// 337.717 us; speedup vs baseline: 1.7802x; 1.0643x over previous
//
#include <hip/hip_runtime.h>

typedef __attribute__((ext_vector_type(4))) float f32x4;
typedef unsigned char u8;
typedef unsigned long long u64t;

#define BIG_NEG -1000000000.0f

static constexpr int B_  = 256;
static constexpr int SX_ = 34;
static constexpr int SY_ = 34;
static constexpr int IND = 66;   // IN_DIM
static constexpr int OP_ = 80;   // padded OUT_DIM (65 -> 80)

__device__ __forceinline__ f32x4 mfma_fp8(long a, long b, f32x4 c) {
  return __builtin_amdgcn_mfma_f32_16x16x32_fp8_fp8(a, b, c, 0, 0, 0);
}
__device__ __forceinline__ float sigm(float x)  { return 1.0f / (1.0f + __expf(-x)); }
__device__ __forceinline__ float tanhx(float x) { return 2.0f * sigm(2.0f * x) - 1.0f; }
template <bool HI>
__device__ __forceinline__ unsigned pk2(float a, float b, unsigned old) {
  return __builtin_amdgcn_cvt_pk_fp8_f32(a, b, (int)old, HI);
}
// select element j (runtime 0..3) of f32x4 without dynamic indexing
__device__ __forceinline__ float rsel(f32x4 a, int j) {
  float lo = (j & 1) ? a[1] : a[0];
  float hi = (j & 1) ? a[3] : a[2];
  return (j & 2) ? hi : lo;
}

// ---------------------------------------------------------------------------
// fused prep kernel: blocks [0,68) decode | [68,228) pad_head |
// [228,356) build_E | [356,3428) conv_fp8 (grid-stride).
// Blocks [0,96) additionally zero the 96KB flag region with plain stores
// (replaces the hipMemsetAsync dispatch; HIP inter-kernel ordering flushes
// them to the coherence point before lstm_persist reads them — verified
// correct in the R9 passing run).
// ---------------------------------------------------------------------------
__global__ __launch_bounds__(256) void prep_all(
    const float* __restrict__ src, const float* __restrict__ tgt,
    int* __restrict__ tok_x, int* __restrict__ tok_y,
    const float* __restrict__ Wsub, const float* __restrict__ Wins,
    u8* __restrict__ Wcat,
    const float* __restrict__ Wihf, const float* __restrict__ bf,
    const float* __restrict__ Wihr, const float* __restrict__ br,
    const float* __restrict__ Wihm, const float* __restrict__ bm,
    float* __restrict__ Ef, float* __restrict__ Er, float* __restrict__ Em,
    const float* __restrict__ Whf, const float* __restrict__ Whr,
    const float* __restrict__ Whm,
    u8* __restrict__ w8f, u8* __restrict__ w8r, u8* __restrict__ w8m,
    unsigned* __restrict__ flagsz) {
  __shared__ float tile[64 * 67];
  const int blk = blockIdx.x;
  const int tid = threadIdx.x;

  // zero flags: 768*32 u32 = 24576 = 96 blocks x 256 threads
  if (blk < 96) flagsz[blk * 256 + tid] = 0;

  if (blk < 68) {                       // ---- decode tokens ----
    int idx = blk * 256 + tid;
    const int half = SX_ * B_;
    const float* base = (idx < half) ? src : tgt;
    int* outp         = (idx < half) ? tok_x : tok_y;
    int k = (idx < half) ? idx : idx - half;
    const float* p = base + (size_t)k * IND;
    int tok = -1;
    for (int v = 0; v < IND; ++v) if (p[v] > 0.5f) tok = v;
    outp[k] = tok;
  } else if (blk < 228) {               // ---- pad head W -> fp8 ----
    int widx = (blk - 68) * 256 + tid;
    int row = widx >> 8;
    int wc  = widx & 255;
    int srow = row < 80 ? row : row - 80;
    const float* W = row < 80 ? Wsub : Wins;
    float f0 = 0.f, f1 = 0.f, f2 = 0.f, f3 = 0.f;
    if (srow < 65) {
      const float* p = W + (size_t)srow * 1024 + wc * 4;
      f0 = p[0]; f1 = p[1]; f2 = p[2]; f3 = p[3];
    }
    unsigned w = pk2<false>(f0, f1, 0);
    w = pk2<true>(f2, f3, w);
    ((unsigned*)Wcat)[widx] = w;
  } else if (blk < 356) {               // ---- build E (LDS transpose) ----
    int tb = blk - 228;
    const float* W; const float* bias; float* E; int H4; int n0;
    if (tb < 32)      { W = Wihf; bias = bf; E = Ef; H4 = 2048; n0 = tb * 64; }
    else if (tb < 64) { W = Wihr; bias = br; E = Er; H4 = 2048; n0 = (tb - 32) * 64; }
    else              { W = Wihm; bias = bm; E = Em; H4 = 4096; n0 = (tb - 64) * 64; }
    const float* s2 = W + (size_t)n0 * IND;
    for (int i = tid; i < 64 * IND; i += 256) {
      int n = i / IND, v = i - n * IND;
      tile[n * 67 + v] = s2[i];
    }
    __syncthreads();
    int lane = tid & 63, w2 = tid >> 6;
    float bl = bias[n0 + lane];
    for (int v = w2; v < 67; v += 4) {
      float val = (v < 66 ? tile[lane * 67 + v] : 0.f) + bl;
      E[(size_t)v * H4 + n0 + lane] = val;
    }
  } else {                              // ---- conv Whh -> fp8 ----
    const int F4 = 2048 * 512 / 4;
    const int M4 = 4096 * 1024 / 4;
    int i = (blk - 356) * 256 + tid;
    int stride = 3072 * 256;
    for (; i < 2 * F4 + M4; i += stride) {
      const float* s3; unsigned* dst; int k;
      if (i < F4)          { s3 = Whf; dst = (unsigned*)w8f; k = i; }
      else if (i < 2 * F4) { s3 = Whr; dst = (unsigned*)w8r; k = i - F4; }
      else                 { s3 = Whm; dst = (unsigned*)w8m; k = i - 2 * F4; }
      float4 f = ((const float4*)s3)[k];
      unsigned w3 = pk2<false>(f.x, f.y, 0);
      w3 = pk2<true>(f.z, f.w, w3);
      dst[k] = w3;
    }
  }
}

// ---------------------------------------------------------------------------
// persistent LSTM, 768 blocks x 256 thr, 3 blocks/CU — EXACT R3 structure
// (best measured: 190.9-193.6 us). mod: 512 blocks (32b x 16u);
// fwd/rev: 128+128 (32b x 32u). Flag protocol: store h (relaxed agent
// atomics) -> vmcnt(0) -> syncthreads -> fire flag; consumer polls flags
// then stages with 8B relaxed agent atomic loads (LLC-direct), AST = HH+8.
// ---------------------------------------------------------------------------
template <int HH, int NS>
__device__ __forceinline__ void run_lstm32(
    const u8* __restrict__ w8, const float* __restrict__ E,
    bool revr, u8* __restrict__ hall, int b0, int h0,
    unsigned* __restrict__ flags, int dom0, int myid,
    u8* __restrict__ alds, u8* __restrict__ hT, const u8* __restrict__ tok_small) {
  const int tid = threadIdx.x;
  const int lane = tid & 63, w = tid >> 6;
  const int lo = lane & 15, q = lane >> 4;
  constexpr int AST = HH + 8;
  constexpr int U8C = HH / 8;
  constexpr int USH = (HH == 1024) ? 7 : 6;
  constexpr int NI  = (32 * U8C) / 256;   // 8 for HH=512
  constexpr int NK  = HH / 32;
  const int hh = lo & 7;
  const bool hi = (lo >= 8);
  const int hu_e = h0 + w * 8 + hh;

  long breg0[NK], breg1[NK];
  {
    const u8* brow0 = w8 + (size_t)((lo >> 3) * HH + hu_e) * HH + q * 8;
    const u8* brow1 = w8 + (size_t)((2 + (lo >> 3)) * HH + hu_e) * HH + q * 8;
#pragma unroll
    for (int kk = 0; kk < NK; ++kk) {
      breg0[kk] = *(const long*)(brow0 + kk * 32);
      breg1[kk] = *(const long*)(brow1 + kk * 32);
    }
  }
  float creg[4] = {0.f, 0.f, 0.f, 0.f};

  for (int t = 0; t < 34; ++t) {
    const int tpos = revr ? 33 - t : t;
    const u8* tkp = tok_small + tpos * 32;

    // hoisted E-gather (issues before poll; latency hides under it)
    float ev[2][4][2];
#pragma unroll
    for (int mt = 0; mt < 2; ++mt)
#pragma unroll
      for (int rr = 0; rr < 2; ++rr) {
        int r = (hi ? 2 : 0) + rr;
        int v = tkp[mt * 16 + q * 4 + r];
        const float* e = E + (size_t)v * (4 * HH) + hu_e;
        ev[mt][0][rr] = e[0];
        ev[mt][1][rr] = e[HH];
        ev[mt][2][rr] = e[2 * HH];
        ev[mt][3][rr] = e[3 * HH];
      }

    f32x4 acc[2][2];
#pragma unroll
    for (int mt = 0; mt < 2; ++mt) {
      acc[mt][0] = (f32x4){0.f, 0.f, 0.f, 0.f};
      acc[mt][1] = (f32x4){0.f, 0.f, 0.f, 0.f};
    }

    if (t > 0) {
      if (tid < NS) {
        const unsigned tgt = (unsigned)t;
        int spin = 0;
        for (;;) {
          unsigned v = __hip_atomic_load(&flags[(dom0 + tid) * 32],
                                         __ATOMIC_RELAXED, __HIP_MEMORY_SCOPE_AGENT);
          if (__ballot(v < tgt) == 0) break;
          __builtin_amdgcn_s_sleep(1);
          if (++spin > (1 << 17)) break;
        }
      }
      __syncthreads();

      const u8* hsrc = hall + (size_t)t * (256 * HH);
      u64t tmp[NI];
#pragma unroll
      for (int ii = 0; ii < NI; ++ii) {
        int idx = tid + ii * 256;
        tmp[ii] = __hip_atomic_load(
            (const u64t*)(hsrc + (size_t)(b0 + (idx >> USH)) * HH + (idx & (U8C - 1)) * 8),
            __ATOMIC_RELAXED, __HIP_MEMORY_SCOPE_AGENT);
      }
#pragma unroll
      for (int ii = 0; ii < NI; ++ii) {
        int idx = tid + ii * 256;
        *(u64t*)&alds[(idx >> USH) * AST + (idx & (U8C - 1)) * 8] = tmp[ii];
      }
      __syncthreads();

      const u8* a0p = alds + lo * AST + q * 8;
      const u8* a1p = alds + (16 + lo) * AST + q * 8;
#pragma unroll
      for (int kk = 0; kk < NK; ++kk) {
        long a0 = *(const long*)(a0p + kk * 32);
        long a1 = *(const long*)(a1p + kk * 32);
        acc[0][0] = mfma_fp8(a0, breg0[kk], acc[0][0]);
        acc[0][1] = mfma_fp8(a0, breg1[kk], acc[0][1]);
        acc[1][0] = mfma_fp8(a1, breg0[kk], acc[1][0]);
        acc[1][1] = mfma_fp8(a1, breg1[kk], acc[1][1]);
      }
    }

#pragma unroll
    for (int mt = 0; mt < 2; ++mt) {
      f32x4 t0 = acc[mt][0], t1 = acc[mt][1];
      f32x4 p0, p1;
#pragma unroll
      for (int c2 = 0; c2 < 4; ++c2) {
        p0[c2] = __shfl_xor(t0[c2], 8, 64);
        p1[c2] = __shfl_xor(t1[c2], 8, 64);
      }
#pragma unroll
      for (int rr = 0; rr < 2; ++rr) {
        int r = (hi ? 2 : 0) + rr;
        float iv = (hi ? p0[r] : t0[r]) + ev[mt][0][rr];
        float fv = (hi ? t0[r] : p0[r]) + ev[mt][1][rr];
        float gv = (hi ? p1[r] : t1[r]) + ev[mt][2][rr];
        float ov = (hi ? t1[r] : p1[r]) + ev[mt][3][rr];
        int m = mt * 16 + q * 4 + r;
        float cold = creg[mt * 2 + rr];
        float cn = sigm(fv) * cold + sigm(iv) * tanhx(gv);
        float hn = sigm(ov) * tanhx(cn);
        creg[mt * 2 + rr] = cn;
        hT[m * 32 + w * 8 + hh] = (u8)(pk2<false>(hn, hn, 0) & 0xffu);
      }
    }
    __syncthreads();

    {
      int m = tid >> 3, cc = tid & 7;
      unsigned val = *(const unsigned*)&hT[m * 32 + cc * 4];
      u8* hdst = hall + (size_t)(t + 1) * (256 * HH);
      __hip_atomic_store((unsigned*)(hdst + (size_t)(b0 + m) * HH + h0 + cc * 4),
                         val, __ATOMIC_RELAXED, __HIP_MEMORY_SCOPE_AGENT);
    }
    if (t < 33) {
      __asm__ volatile("s_waitcnt vmcnt(0)" ::: "memory");
      __syncthreads();
      if (tid == 0)
        __hip_atomic_store(&flags[(dom0 + myid) * 32], (unsigned)(t + 1),
                           __ATOMIC_RELAXED, __HIP_MEMORY_SCOPE_AGENT);
    }
  }
}

template <int HH, int NS>
__device__ __forceinline__ void run_lstm16(
    const u8* __restrict__ w8, const float* __restrict__ E,
    u8* __restrict__ hall, int b0, int h0,
    unsigned* __restrict__ flags, int dom0, int myid,
    u8* __restrict__ alds, u8* __restrict__ hT, const u8* __restrict__ tok_small) {
  const int tid = threadIdx.x;
  const int lane = tid & 63, w = tid >> 6;
  const int lo = lane & 15, q = lane >> 4;
  constexpr int AST = HH + 8;
  constexpr int U8C = HH / 8;          // 128
  constexpr int USH = 7;               // HH = 1024
  constexpr int NI  = (32 * U8C) / 256;   // 16
  constexpr int NK  = HH / 32;         // 32
  const int g = lo & 3;                // gate index (col low bits)
  const int u = lo >> 2;               // unit within wave's 4
  const int hu = h0 + w * 4 + u;       // absolute h-unit

  long breg[NK];
  {
    const u8* brow = w8 + (size_t)(g * HH + hu) * HH + q * 8;
#pragma unroll
    for (int kk = 0; kk < NK; ++kk) breg[kk] = *(const long*)(brow + kk * 32);
  }
  float creg[2] = {0.f, 0.f};

  for (int t = 0; t < 34; ++t) {
    const u8* tkp = tok_small + t * 32;

    float ev[2][4];
#pragma unroll
    for (int mt = 0; mt < 2; ++mt) {
      int v = tkp[mt * 16 + q * 4 + g];
      const float* e = E + (size_t)v * (4 * HH) + hu;
      ev[mt][0] = e[0]; ev[mt][1] = e[HH]; ev[mt][2] = e[2 * HH]; ev[mt][3] = e[3 * HH];
    }

    f32x4 acc[2];
    acc[0] = (f32x4){0.f, 0.f, 0.f, 0.f};
    acc[1] = (f32x4){0.f, 0.f, 0.f, 0.f};

    if (t > 0) {
      if (tid < NS) {
        const unsigned tgt = (unsigned)t;
        int spin = 0;
        for (;;) {
          unsigned v = __hip_atomic_load(&flags[(dom0 + tid) * 32],
                                         __ATOMIC_RELAXED, __HIP_MEMORY_SCOPE_AGENT);
          if (__ballot(v < tgt) == 0) break;
          __builtin_amdgcn_s_sleep(1);
          if (++spin > (1 << 17)) break;
        }
      }
      __syncthreads();

      const u8* hsrc = hall + (size_t)t * (256 * HH);
      u64t tmp[NI];
#pragma unroll
      for (int ii = 0; ii < NI; ++ii) {
        int idx = tid + ii * 256;
        tmp[ii] = __hip_atomic_load(
            (const u64t*)(hsrc + (size_t)(b0 + (idx >> USH)) * HH + (idx & (U8C - 1)) * 8),
            __ATOMIC_RELAXED, __HIP_MEMORY_SCOPE_AGENT);
      }
#pragma unroll
      for (int ii = 0; ii < NI; ++ii) {
        int idx = tid + ii * 256;
        *(u64t*)&alds[(idx >> USH) * AST + (idx & (U8C - 1)) * 8] = tmp[ii];
      }
      __syncthreads();

      const u8* a0p = alds + lo * AST + q * 8;
      const u8* a1p = alds + (16 + lo) * AST + q * 8;
#pragma unroll
      for (int kk = 0; kk < NK; ++kk) {
        long a0 = *(const long*)(a0p + kk * 32);
        long a1 = *(const long*)(a1p + kk * 32);
        acc[0] = mfma_fp8(a0, breg[kk], acc[0]);
        acc[1] = mfma_fp8(a1, breg[kk], acc[1]);
      }
    }

    // ---- epilogue: 4-gate butterfly (xor 1/2/3), 2 cells per lane ----
#pragma unroll
    for (int mt = 0; mt < 2; ++mt) {
      f32x4 a = acc[mt];
      float own = rsel(a, g);
      float y1  = __shfl_xor(rsel(a, g ^ 1), 1, 64);
      float y2  = __shfl_xor(rsel(a, g ^ 2), 2, 64);
      float y3  = __shfl_xor(rsel(a, g ^ 3), 3, 64);
      float iv = (g == 0) ? own : (g == 1) ? y1 : (g == 2) ? y2 : y3;
      float fv = (g == 0) ? y1 : (g == 1) ? own : (g == 2) ? y3 : y2;
      float gv = (g == 0) ? y2 : (g == 1) ? y3 : (g == 2) ? own : y1;
      float ov = (g == 0) ? y3 : (g == 1) ? y2 : (g == 2) ? y1 : own;
      iv += ev[mt][0]; fv += ev[mt][1]; gv += ev[mt][2]; ov += ev[mt][3];
      int m = mt * 16 + q * 4 + g;
      float cold = creg[mt];
      float cn = sigm(fv) * cold + sigm(iv) * tanhx(gv);
      float hn = sigm(ov) * tanhx(cn);
      creg[mt] = cn;
      hT[m * 16 + w * 4 + u] = (u8)(pk2<false>(hn, hn, 0) & 0xffu);
    }
    __syncthreads();

    if (tid < 128) {
      int m = tid >> 2, cc = tid & 3;
      unsigned val = *(const unsigned*)&hT[m * 16 + cc * 4];
      u8* hdst = hall + (size_t)(t + 1) * (256 * HH);
      __hip_atomic_store((unsigned*)(hdst + (size_t)(b0 + m) * HH + h0 + cc * 4),
                         val, __ATOMIC_RELAXED, __HIP_MEMORY_SCOPE_AGENT);
    }
    if (t < 33) {
      __asm__ volatile("s_waitcnt vmcnt(0)" ::: "memory");
      __syncthreads();
      if (tid == 0)
        __hip_atomic_store(&flags[(dom0 + myid) * 32], (unsigned)(t + 1),
                           __ATOMIC_RELAXED, __HIP_MEMORY_SCOPE_AGENT);
    }
  }
}

__global__ __launch_bounds__(256, 3) void lstm_persist(
    const int* __restrict__ tok_x, const int* __restrict__ tok_y,
    const float* __restrict__ E_f, const u8* __restrict__ w8_f,
    const float* __restrict__ E_r, const u8* __restrict__ w8_r,
    const float* __restrict__ E_m, const u8* __restrict__ w8_m,
    u8* __restrict__ fwd_all, u8* __restrict__ rev_all, u8* __restrict__ y_all,
    unsigned* __restrict__ flags) {
  __shared__ u8 alds[32 * 1032] __attribute__((aligned(16)));  // 33 KB stage
  __shared__ u8 hT[32 * 32] __attribute__((aligned(16)));      // transpose buf
  __shared__ u8 tok_small[34 * 32];    // this block's tokens (66 = none)

  const int b = blockIdx.x;
  // blocks [0,512): mod (2 per CU); [512,640): fwd; [640,768): rev (1 per CU)
  int role, c, s;
  if (b < 512)      { role = 2; c = b >> 6; s = b & 63; }
  else if (b < 640) { int l = b - 512; role = 0; c = l >> 4; s = l & 15; }
  else              { int l = b - 640; role = 1; c = l >> 4; s = l & 15; }

  const float* E  = role == 0 ? E_f  : role == 1 ? E_r  : E_m;
  const u8*    w8 = role == 0 ? w8_f : role == 1 ? w8_r : w8_m;
  u8* hall        = role == 0 ? fwd_all : role == 1 ? rev_all : y_all;
  const int* tokg = (role == 2) ? tok_y : tok_x;
  const int b0 = c * 32;
  // flag layout: mod domains [0,512), fwd [512,640), rev [640,768)
  int dom0, h0;
  if (role == 2)      { dom0 = c * 64;       h0 = s * 16; }
  else if (role == 0) { dom0 = 512 + c * 16; h0 = s * 32; }
  else                { dom0 = 640 + c * 16; h0 = s * 32; }

  for (int i = threadIdx.x; i < 34 * 32; i += 256) {
    int t2 = i >> 5, m = i & 31;
    int tk = tokg[t2 * 256 + b0 + m];
    tok_small[i] = (u8)(tk < 0 ? 66 : tk);
  }
  __syncthreads();

  if (role == 2)
    run_lstm16<1024, 64>(w8, E, hall, b0, h0, flags, dom0, s, alds, hT, tok_small);
  else
    run_lstm32<512, 16>(w8, E, role == 1, hall, b0, h0, flags, dom0, s, alds, hT,
                        tok_small);
}

// ---------------------------------------------------------------------------
// head: lx = x_emb @ W^T, ly = y_emb @ W^T + b, both heads (W rows 0..159).
// 272 blocks x 256 thr; 64 rows/block (1 m-tile/wave); A-loads before W-stage.
// ---------------------------------------------------------------------------
__global__ __launch_bounds__(256, 1) void head_kernel(
    const u8* __restrict__ fwd_all, const u8* __restrict__ rev_all,
    const u8* __restrict__ y_all, const u8* __restrict__ Wcat,
    const float* __restrict__ b_sub, const float* __restrict__ b_ins,
    float* __restrict__ lx_sub, float* __restrict__ lx_ins,
    float* __restrict__ ly_sub, float* __restrict__ ly_ins) {
  __shared__ u8 wq[160 * 264];   // 42240 B, row pad 264 for bank spread
  const int lane = threadIdx.x & 63, wave = threadIdx.x >> 6;
  const int lo = lane & 15, q = lane >> 4;
  int blk = blockIdx.x;
  bool yside = (blk >= 136);
  int mb = yside ? blk - 136 : blk;
  int ij = mb >> 2;
  int bbase = (mb & 3) * 64;

  f32x4 acc[10];
#pragma unroll
  for (int nn = 0; nn < 10; ++nn) acc[nn] = (f32x4){0.f,0.f,0.f,0.f};

  for (int qk = 0; qk < 4; ++qk) {
    long aA[8];
    {
      int row = bbase + wave * 16 + lo;
      const u8* ab;
      if (yside)
        ab = y_all + ((size_t)(ij + 1) * 256 + row) * 1024 + qk * 256 + q * 8;
      else if (qk < 2)
        ab = fwd_all + ((size_t)(ij + 1) * 256 + row) * 512 + qk * 256 + q * 8;
      else
        ab = rev_all + ((size_t)(34 - ij) * 256 + row) * 512 + (qk - 2) * 256 + q * 8;
#pragma unroll
      for (int ki = 0; ki < 8; ++ki) aA[ki] = *(const long*)(ab + ki * 32);
    }

    for (int c8 = threadIdx.x; c8 < 160 * 32; c8 += 256) {
      int row = c8 >> 5, col = (c8 & 31) << 3;
      *(long*)&wq[row * 264 + col] =
          *(const long*)&Wcat[(size_t)row * 1024 + qk * 256 + col];
    }
    __syncthreads();

#pragma unroll
    for (int ki = 0; ki < 8; ++ki) {
#pragma unroll
      for (int nn = 0; nn < 10; ++nn) {
        long bf = *(const long*)&wq[(nn * 16 + lo) * 264 + ki * 32 + q * 8];
        acc[nn] = mfma_fp8(aA[ki], bf, acc[nn]);
      }
    }
    __syncthreads();
  }

#pragma unroll
  for (int nn = 0; nn < 10; ++nn) {
    bool is_sub = (nn < 5);
    int n = (is_sub ? nn : nn - 5) * 16 + lo;
    float bias = 0.0f;
    if (yside && n < 65) bias = is_sub ? b_sub[n] : b_ins[n];
    float* dst = yside ? (is_sub ? ly_sub : ly_ins) : (is_sub ? lx_sub : lx_ins);
#pragma unroll
    for (int r = 0; r < 4; ++r) {
      int b = bbase + wave * 16 + q * 4 + r;
      dst[((size_t)ij * 256 + b) * OP_ + n] = acc[nn][r] + bias;
    }
  }
}

// ---------------------------------------------------------------------------
// pair: split by HEAD to kill register spill. grid 272 = head{sub,ins} x 34 i
// x 4 b-chunks; block 256 thr (64 b x 4 j-lanes). X (one head) in regs.
//   sub pass -> ch1 (sub), ch3 (del);  ins pass -> ch0 (ins), ch2 (end)
// ---------------------------------------------------------------------------
__device__ __forceinline__ void lse_one(const float4* __restrict__ X,
                                        const float* __restrict__ py, int sym,
                                        float& logZ, float& v64, float& vs) {
  float v[68];
  const float4* py4 = (const float4*)py;
#pragma unroll
  for (int q = 0; q < 17; ++q) {
    float4 yb = py4[q];
    v[4 * q + 0] = X[q].x + yb.x;
    v[4 * q + 1] = X[q].y + yb.y;
    v[4 * q + 2] = X[q].z + yb.z;
    v[4 * q + 3] = X[q].w + yb.w;
  }
  float m = v[0];
#pragma unroll
  for (int o = 1; o < 65; ++o) m = fmaxf(m, v[o]);
  float s = 0.0f, vsl = 0.0f;
#pragma unroll
  for (int o = 0; o < 65; ++o) {
    s += __expf(v[o] - m);
    if (o < 64) vsl = (o == sym) ? v[o] : vsl;
  }
  logZ = m + __logf(s);
  v64 = v[64];
  vs = vsl;
}

__global__ __launch_bounds__(256, 1) void pair_kernel(
    const int* __restrict__ tok_x, const int* __restrict__ tok_y,
    const float* __restrict__ lx_sub, const float* __restrict__ lx_ins,
    const float* __restrict__ ly_sub, const float* __restrict__ ly_ins,
    float* __restrict__ out) {
  const int hsel = blockIdx.x >= 136;
  const int rem = hsel ? blockIdx.x - 136 : blockIdx.x;
  const int i = rem >> 2;
  const int bc = rem & 3;
  const int jq = threadIdx.x >> 6;
  const int bl = threadIdx.x & 63;
  const int b = bc * 64 + bl;
  const size_t CH = (size_t)SX_ * SY_ * B_;
  const float* lx = hsel ? lx_ins : lx_sub;
  const float* ly = hsel ? ly_ins : ly_sub;
  // sub: chA=1 (sub), chB=3 (del); ins: chA=0 (ins), chB=2 (end)
  float* outA = out + (hsel ? 0 : CH);
  float* outB = out + (hsel ? 2 * CH : 3 * CH);

  float4 X[17];
  {
    const float4* ps = (const float4*)(lx + ((size_t)i * 256 + b) * OP_);
#pragma unroll
    for (int q = 0; q < 17; ++q) X[q] = ps[q];
  }
  int tx = tok_x[i * 256 + b];

  for (int j = jq; j < 34; j += 4) {
    size_t obase = ((size_t)i * SY_ + j) * 256 + b;
    bool dead = (j == SY_ - 1) || (tx < 0);
    if (!dead) {
      int ty = tok_y[j * 256 + b];
      if (ty < 0) dead = true;
    }
    if (dead) {
      outA[obase] = BIG_NEG;
      outB[obase] = BIG_NEG;
      continue;
    }
    int tn = tok_y[(j + 1) * 256 + b];
    bool ins_ok = (tn != 65);
    int sym = (tn >= 0 && tn < 64) ? tn : -1;

    float logZ, v64, vs;
    lse_one(X, ly + ((size_t)j * 256 + b) * OP_, sym, logZ, v64, vs);
    float valB = v64 - logZ;                       // del (sub) / end (ins)
    float valA = (sym >= 0) ? (vs - logZ) : 0.0f;  // sub / ins value
    outA[obase] = ins_ok ? valA : BIG_NEG;
    outB[obase] = valB;
  }
}

// ---------------------------------------------------------------------------
// launch: 4 dispatches (prep zeroes flags; no memset node)
// ---------------------------------------------------------------------------
extern "C" void kernel_launch(void* const* d_in, const int* in_sizes, int n_in,
                              void* d_out, int out_size, void* d_ws, size_t ws_size,
                              hipStream_t stream) {
  const float* sources = (const float*)d_in[0];
  const float* targets = (const float*)d_in[1];
  const float* Wih_f = (const float*)d_in[2];
  const float* Whh_f = (const float*)d_in[3];
  const float* b_f   = (const float*)d_in[4];
  const float* Wih_r = (const float*)d_in[5];
  const float* Whh_r = (const float*)d_in[6];
  const float* b_r   = (const float*)d_in[7];
  const float* Wih_m = (const float*)d_in[8];
  const float* Whh_m = (const float*)d_in[9];
  const float* b_m   = (const float*)d_in[10];
  const float* W_sub = (const float*)d_in[11];
  const float* b_sub = (const float*)d_in[12];
  const float* W_ins = (const float*)d_in[13];
  const float* b_ins = (const float*)d_in[14];
  float* out = (float*)d_out;

  char* w = (char*)d_ws;
  constexpr size_t FLAG_SZ = (size_t)768 * 32 * 4;          // 96 KB, 128B-spread
  constexpr size_t TOK_SZ  = (size_t)SX_ * B_ * 4;
  constexpr size_t WCAT_SZ = (size_t)160 * 1024;            // head W fp8
  constexpr size_t W8F_SZ  = (size_t)2048 * 512;            // fwd Whh fp8
  constexpr size_t W8M_SZ  = (size_t)4096 * 1024;           // mod Whh fp8
  constexpr size_t EF_SZ   = (size_t)67 * 2048 * 4;         // E tables f32
  constexpr size_t EM_SZ   = (size_t)67 * 4096 * 4;
  constexpr size_t LX_SZ   = (size_t)SX_ * B_ * OP_ * 4;
  constexpr size_t HF_SZ   = (size_t)35 * B_ * 512;         // h slabs fp8
  constexpr size_t HM_SZ   = (size_t)35 * B_ * 1024;

  size_t off = 0;
  unsigned* flags = (unsigned*)(w + off); off += FLAG_SZ;
  int*  tok_x   = (int*)(w + off);  off += TOK_SZ;
  int*  tok_y   = (int*)(w + off);  off += TOK_SZ;
  off = (off + 255) & ~(size_t)255;
  u8*   Wcat    = (u8*)(w + off);   off += WCAT_SZ;
  u8*   w8_f    = (u8*)(w + off);   off += W8F_SZ;
  u8*   w8_r    = (u8*)(w + off);   off += W8F_SZ;
  u8*   w8_m    = (u8*)(w + off);   off += W8M_SZ;
  float* E_f    = (float*)(w + off); off += EF_SZ;
  float* E_r    = (float*)(w + off); off += EF_SZ;
  float* E_m    = (float*)(w + off); off += EM_SZ;
  float* lx_sub = (float*)(w + off); off += LX_SZ;
  float* lx_ins = (float*)(w + off); off += LX_SZ;
  float* ly_sub = (float*)(w + off); off += LX_SZ;
  float* ly_ins = (float*)(w + off); off += LX_SZ;
  u8* fwd_all   = (u8*)(w + off);   off += HF_SZ;
  u8* rev_all   = (u8*)(w + off);   off += HF_SZ;
  u8* y_all     = (u8*)(w + off);   off += HM_SZ;
  (void)ws_size; (void)in_sizes; (void)n_in; (void)out_size;

  prep_all<<<3428, 256, 0, stream>>>(
      sources, targets, tok_x, tok_y,
      W_sub, W_ins, Wcat,
      Wih_f, b_f, Wih_r, b_r, Wih_m, b_m, E_f, E_r, E_m,
      Whh_f, Whh_r, Whh_m, w8_f, w8_r, w8_m, flags);

  lstm_persist<<<768, 256, 0, stream>>>(
      tok_x, tok_y,
      E_f, w8_f,
      E_r, w8_r,
      E_m, w8_m,
      fwd_all, rev_all, y_all, flags);

  head_kernel<<<272, 256, 0, stream>>>(fwd_all, rev_all, y_all, Wcat,
                                       b_sub, b_ins, lx_sub, lx_ins, ly_sub, ly_ins);

  pair_kernel<<<272, 256, 0, stream>>>(tok_x, tok_y, lx_sub, lx_ins,
                                       ly_sub, ly_ins, out);
}